// Round 5
// baseline (4198.746 us; speedup 1.0000x reference)
//
#include <hip/hip_runtime.h>
#include <hip/hip_bf16.h>

#define NN 50000
#define NE 600000
#define D 128
#define NL 5

typedef __hip_bfloat16 bf16;

__device__ __forceinline__ float b2f(bf16 v) { return __bfloat162float(v); }

// float-tensor load: runtime flag selects f32 vs bf16 interpretation
__device__ __forceinline__ float loadF(const void* p, long long i, int isf32) {
    if (isf32) return ((const float*)p)[i];
    return b2f(((const bf16*)p)[i]);
}

// If the float tensors are f32, bf16-interpreting the raw halfwords gives
// uniformly random exponents (~44% huge/NaN per low half). Genuine bf16
// N(0,0.05) data stays |v| < 0.5 (exponent < 0x7F).
__global__ void detect_k(const void* __restrict__ atom, int* __restrict__ flag) {
    __shared__ int vote;
    if (threadIdx.x == 0) vote = 0;
    __syncthreads();
    unsigned short u = ((const unsigned short*)atom)[threadIdx.x];
    unsigned short ex = (u >> 7) & 0xFF;
    if (ex >= 0x90) atomicOr(&vote, 1);
    __syncthreads();
    if (threadIdx.x == 0) *flag = vote;
}

__global__ void zero_k(float* __restrict__ p, int n) {
    int i = blockIdx.x * 256 + threadIdx.x;
    if (i < n) p[i] = 0.f;
}

__global__ void embed_k(const int* __restrict__ x,
                        const void* __restrict__ atom,
                        const void* __restrict__ chir,
                        const void* __restrict__ hyb,
                        const int* __restrict__ fl,
                        float* __restrict__ h) {
    int isf32 = *fl;
    int idx = blockIdx.x * 256 + threadIdx.x;
    if (idx >= NN * D) return;
    int n = idx >> 7, f = idx & 127;
    h[idx] = loadF(atom, (long long)x[n * 3 + 0] * D + f, isf32) +
             loadF(chir, (long long)x[n * 3 + 1] * D + f, isf32) +
             loadF(hyb,  (long long)x[n * 3 + 2] * D + f, isf32);
}

__global__ void scatter_k(const float* __restrict__ h,
                          const int* __restrict__ ei,
                          const int* __restrict__ ea,
                          const void* __restrict__ e1,
                          const void* __restrict__ e2,
                          const int* __restrict__ fl,
                          int layer,
                          float* __restrict__ agg) {
    int isf32 = *fl;
    long long e1off = (long long)layer * 6 * D;
    long long e2off = (long long)layer * 4 * D;
    long long t = (long long)blockIdx.x * 256 + threadIdx.x;
    int e = (int)(t >> 7);
    int j = (int)(t & 127);
    if (e >= NE) return;
    int src = ei[e];
    int dst = ei[NE + e];
    int a0 = ea[2 * e];
    int a1 = ea[2 * e + 1];
    float val = h[(long long)src * D + j] +
                loadF(e1, e1off + a0 * D + j, isf32) +
                loadF(e2, e2off + a1 * D + j, isf32);
    atomicAdd(&agg[(long long)dst * D + j], val);
}

// one block (256 thr) per node: h2 = ReLU(agg @ W1 + b1) @ W2 + b2, in-place
__global__ void mlp_k(float* __restrict__ agg,
                      const void* __restrict__ W1,
                      const void* __restrict__ b1,
                      const void* __restrict__ W2,
                      const void* __restrict__ b2,
                      const int* __restrict__ fl,
                      int layer) {
    __shared__ float a[D];
    __shared__ float mid[2 * D];
    int isf32 = *fl;
    long long w1off = (long long)layer * D * 2 * D;
    long long b1off = (long long)layer * 2 * D;
    long long w2off = (long long)layer * 2 * D * D;
    long long b2off = (long long)layer * D;
    int n = blockIdx.x;
    int tid = threadIdx.x;
    if (tid < D) a[tid] = agg[(long long)n * D + tid];
    __syncthreads();
    float acc = loadF(b1, b1off + tid, isf32);
#pragma unroll 8
    for (int j = 0; j < D; ++j) acc += a[j] * loadF(W1, w1off + j * 2 * D + tid, isf32);
    mid[tid] = fmaxf(acc, 0.f);
    __syncthreads();
    if (tid < D) {
        float acc2 = loadF(b2, b2off + tid, isf32);
#pragma unroll 8
        for (int k = 0; k < 2 * D; ++k)
            acc2 += mid[k] * loadF(W2, w2off + k * D + tid, isf32);
        agg[(long long)n * D + tid] = acc2;
    }
}

__global__ void bnstats_k(const float* __restrict__ h2, float* __restrict__ stats) {
    __shared__ float ss[256];
    __shared__ float sq[256];
    int tid = threadIdx.x;
    float s = 0.f, q = 0.f;
    int stride = gridDim.x * 256;  // multiple of 128 -> feature fixed per thread
    for (int idx = blockIdx.x * 256 + tid; idx < NN * D; idx += stride) {
        float v = h2[idx];
        s += v;
        q += v * v;
    }
    ss[tid] = s;
    sq[tid] = q;
    __syncthreads();
    if (tid < D) {
        atomicAdd(&stats[tid], ss[tid] + ss[tid + D]);
        atomicAdd(&stats[D + tid], sq[tid] + sq[tid + D]);
    }
}

// normalize + affine (+ ReLU on non-last layers); always writes f32
__global__ void bnnorm_k(const float* __restrict__ h2,
                         const float* __restrict__ stats,
                         const void* __restrict__ gamma,
                         const void* __restrict__ beta,
                         const int* __restrict__ fl,
                         int layer,
                         float* __restrict__ hout,
                         int relu) {
    int isf32 = *fl;
    long long goff = (long long)layer * D;
    int idx = blockIdx.x * 256 + threadIdx.x;
    if (idx >= NN * D) return;
    int f = idx & 127;
    float mu = stats[f] * (1.f / NN);
    float var = fmaxf(stats[D + f] * (1.f / NN) - mu * mu, 0.f);
    float rs = rsqrtf(var + 1e-5f);
    float v = (h2[idx] - mu) * rs * loadF(gamma, goff + f, isf32) +
              loadF(beta, goff + f, isf32);
    if (relu) v = fmaxf(v, 0.f);
    hout[idx] = v;
}

extern "C" void kernel_launch(void* const* d_in, const int* in_sizes, int n_in,
                              void* d_out, int out_size, void* d_ws, size_t ws_size,
                              hipStream_t stream) {
    const int* x     = (const int*)d_in[0];
    const int* ei    = (const int*)d_in[1];
    const int* ea    = (const int*)d_in[2];
    const void* atom = d_in[3];
    const void* chir = d_in[4];
    const void* hyb  = d_in[5];
    const void* e1   = d_in[6];
    const void* e2   = d_in[7];
    const void* W1   = d_in[8];
    const void* b1   = d_in[9];
    const void* W2   = d_in[10];
    const void* b2   = d_in[11];
    const void* gm   = d_in[12];
    const void* bt   = d_in[13];

    const size_t ND = (size_t)NN * D;
    const int ND_BLOCKS = (NN * D + 255) / 256;                    // 25000
    const int SC_BLOCKS = (int)(((long long)NE * D + 255) / 256);  // 300000

    // Layout A (ws >= 2*ND*4 + 4KB): [stats][flag][h f32][agg f32] in ws
    // Layout B: [stats][flag][agg f32] in ws; h f32 staged inside d_out
    //           (d_out is NN*D f32 = 25.6MB; h fully consumed before the
    //            final bnnorm overwrites d_out)
    bool big = ws_size >= (2 * ND * sizeof(float) + 4096);

    float* stats = (float*)d_ws;
    int* flag    = (int*)((char*)d_ws + 1024);
    float* h;
    float* agg;

    if (big) {
        h   = (float*)((char*)d_ws + 2048);
        agg = h + ND;
    } else {
        agg = (float*)((char*)d_ws + 2048);
        h   = (float*)d_out;
    }

    detect_k<<<1, 256, 0, stream>>>(atom, flag);
    embed_k<<<ND_BLOCKS, 256, 0, stream>>>(x, atom, chir, hyb, flag, h);

    for (int l = 0; l < NL; ++l) {
        zero_k<<<ND_BLOCKS, 256, 0, stream>>>(agg, NN * D);
        zero_k<<<1, 256, 0, stream>>>(stats, 2 * D);
        scatter_k<<<SC_BLOCKS, 256, 0, stream>>>(h, ei, ea, e1, e2, flag, l, agg);
        mlp_k<<<NN, 256, 0, stream>>>(agg, W1, b1, W2, b2, flag, l);
        bnstats_k<<<256, 256, 0, stream>>>(agg, stats);
        int last = (l == NL - 1);
        bnnorm_k<<<ND_BLOCKS, 256, 0, stream>>>(agg, stats, gm, bt, flag, l,
            last ? (float*)d_out : h, last ? 0 : 1);
    }
}

// Round 7
// 2166.063 us; speedup vs baseline: 1.9384x; 1.9384x over previous
//
#include <hip/hip_runtime.h>
#include <hip/hip_bf16.h>

#define NN 50000
#define NE 600000
#define D 128
#define NL 5

typedef __hip_bfloat16 bf16;
typedef unsigned short ushort_t;
typedef __attribute__((ext_vector_type(8))) short short8;
typedef __attribute__((ext_vector_type(4))) float f32x4;

__device__ __forceinline__ float b2f(bf16 v) { return __bfloat162float(v); }

// float-tensor load: runtime flag selects f32 vs bf16 interpretation
__device__ __forceinline__ float loadF(const void* p, long long i, int isf32) {
    if (isf32) return ((const float*)p)[i];
    return b2f(((const bf16*)p)[i]);
}

// f32 -> bf16 bits (RNE), and bf16 bits -> f32
__device__ __forceinline__ ushort_t f2b(float x) {
    union { float f; unsigned u; } v; v.f = x;
    unsigned r = v.u + 0x7FFF + ((v.u >> 16) & 1);
    return (ushort_t)(r >> 16);
}
__device__ __forceinline__ float bits2f(ushort_t h) {
    union { unsigned u; float f; } v; v.u = ((unsigned)h) << 16;
    return v.f;
}

__global__ void detect_k(const void* __restrict__ atom, int* __restrict__ flag) {
    __shared__ int vote;
    if (threadIdx.x == 0) vote = 0;
    __syncthreads();
    unsigned short u = ((const unsigned short*)atom)[threadIdx.x];
    unsigned short ex = (u >> 7) & 0xFF;
    if (ex >= 0x90) atomicOr(&vote, 1);
    __syncthreads();
    if (threadIdx.x == 0) *flag = vote;
}

__global__ void zero_f(float* __restrict__ p, int n) {
    int i = blockIdx.x * 256 + threadIdx.x;
    if (i < n) p[i] = 0.f;
}
__global__ void zero_i(int* __restrict__ p, int n) {
    int i = blockIdx.x * 256 + threadIdx.x;
    if (i < n) p[i] = 0;
}

// ---------------- CSR build ----------------
__global__ void hist_k(const int* __restrict__ ei, int* __restrict__ deg) {
    int e = blockIdx.x * 256 + threadIdx.x;
    if (e < NE) atomicAdd(&deg[ei[NE + e]], 1);
}

__global__ void scan1_k(const int* __restrict__ deg, int* __restrict__ tmp,
                        int* __restrict__ partial) {
    __shared__ int s[256];
    int t = threadIdx.x;
    int i = blockIdx.x * 256 + t;
    int v = (i < NN) ? deg[i] : 0;
    s[t] = v;
    __syncthreads();
    for (int off = 1; off < 256; off <<= 1) {
        int x = (t >= off) ? s[t - off] : 0;
        __syncthreads();
        s[t] += x;
        __syncthreads();
    }
    if (i < NN) tmp[i] = s[t];
    if (t == 255) partial[blockIdx.x] = s[255];
}

__global__ void scan2_k(int* __restrict__ partial, int nb) {
    __shared__ int s[256];
    int t = threadIdx.x;
    int v = (t < nb) ? partial[t] : 0;
    s[t] = v;
    __syncthreads();
    for (int off = 1; off < 256; off <<= 1) {
        int x = (t >= off) ? s[t - off] : 0;
        __syncthreads();
        s[t] += x;
        __syncthreads();
    }
    int excl = s[t] - v;
    __syncthreads();
    if (t < nb) partial[t] = excl;
}

__global__ void scan3_k(const int* __restrict__ tmp, const int* __restrict__ partial,
                        const int* __restrict__ deg,
                        int* __restrict__ row_start, int* __restrict__ next) {
    int i = blockIdx.x * 256 + threadIdx.x;
    if (i >= NN) return;
    int incl = tmp[i] + partial[i >> 8];
    row_start[i + 1] = incl;
    next[i] = incl - deg[i];
    if (i == 0) row_start[0] = 0;
}

// pack src (16b, NN<65536) | combo (src attr pair, 5b) into one int
__global__ void fill_k(const int* __restrict__ ei, const int* __restrict__ ea,
                       int* __restrict__ next, int* __restrict__ csr) {
    int e = blockIdx.x * 256 + threadIdx.x;
    if (e >= NE) return;
    int src = ei[e];
    int dst = ei[NE + e];
    int c = ea[2 * e] * 4 + ea[2 * e + 1];
    int pos = atomicAdd(&next[dst], 1);
    csr[pos] = src | (c << 16);
}

// ---------------- forward ----------------
__global__ void embed_k(const int* __restrict__ x,
                        const void* __restrict__ atom,
                        const void* __restrict__ chir,
                        const void* __restrict__ hyb,
                        const int* __restrict__ fl,
                        float* __restrict__ h) {
    int isf32 = *fl;
    int idx = blockIdx.x * 256 + threadIdx.x;
    if (idx >= NN * D) return;
    int n = idx >> 7, f = idx & 127;
    h[idx] = loadF(atom, (long long)x[n * 3 + 0] * D + f, isf32) +
             loadF(chir, (long long)x[n * 3 + 1] * D + f, isf32) +
             loadF(hyb,  (long long)x[n * 3 + 2] * D + f, isf32);
}

// one wave per node: agg[n,:] = sum_e (h[src,:] + comb[attr,:])
__global__ __launch_bounds__(256) void aggr_k(
        const float* __restrict__ h,
        const int* __restrict__ row_start,
        const int* __restrict__ csr,
        const void* __restrict__ e1, const void* __restrict__ e2,
        const int* __restrict__ fl, int layer,
        float* __restrict__ agg) {
    __shared__ float comb[24 * D];
    int isf32 = *fl;
    long long e1off = (long long)layer * 6 * D;
    long long e2off = (long long)layer * 4 * D;
    for (int i = threadIdx.x; i < 24 * D; i += 256) {
        int c = i >> 7, f = i & 127;
        comb[i] = loadF(e1, e1off + (c >> 2) * D + f, isf32) +
                  loadF(e2, e2off + (c & 3) * D + f, isf32);
    }
    __syncthreads();
    int n = blockIdx.x * 4 + (threadIdx.x >> 6);
    int lane = threadIdx.x & 63;
    int beg = row_start[n], end = row_start[n + 1];
    float v0 = 0.f, v1 = 0.f;
    for (int i = beg; i < end; ++i) {
        int pk = csr[i];
        int src = pk & 0xFFFF;
        int c = pk >> 16;
        const float* hr = h + (long long)src * D;
        v0 += hr[lane]      + comb[c * D + lane];
        v1 += hr[lane + 64] + comb[c * D + lane + 64];
    }
    agg[(long long)n * D + lane]      = v0;
    agg[(long long)n * D + lane + 64] = v1;
}

// GEMM1: mid[NN x 256] = relu(agg[NN x 128] @ W1 + b1), split hi/lo bf16 out.
// One block per 64-row m-tile, full N=256 (4 chunks of 64). Split-precision
// MFMA: 3 products per tile. Block reads its agg rows fully into LDS before
// writing mid_lo over the same bytes (d_out overlay) -> no __restrict__ there.
__global__ __launch_bounds__(256) void gemm1_k(
        const float* agg,
        const void* __restrict__ W1, const void* __restrict__ b1,
        const int* __restrict__ fl, int layer,
        ushort_t* mid_hi, ushort_t* mid_lo) {
    __shared__ ushort_t Ah[64 * 136], Al[64 * 136];
    __shared__ ushort_t Bh[64 * 136], Bl[64 * 136];
    int isf32 = *fl;
    int m0 = blockIdx.x * 64;
    long long w1off = (long long)layer * D * 2 * D;
    long long b1off = (long long)layer * 2 * D;
    for (int i = threadIdx.x; i < 64 * 128; i += 256) {
        int r = i >> 7, c = i & 127;
        int gr = m0 + r;
        float v = (gr < NN) ? agg[(long long)gr * D + c] : 0.f;
        ushort_t hh = f2b(v);
        Ah[r * 136 + c] = hh;
        Al[r * 136 + c] = f2b(v - bits2f(hh));
    }
    int w = threadIdx.x >> 6, lane = threadIdx.x & 63;
    int quad = lane >> 4, l16 = lane & 15;
    for (int nc = 0; nc < 4; ++nc) {
        __syncthreads();  // A staged (nc=0); prior B reads done (nc>0)
        for (int i = threadIdx.x; i < 64 * 128; i += 256) {
            int nl = i & 63, k = i >> 6;
            float v = loadF(W1, w1off + (long long)k * 256 + nc * 64 + nl, isf32);
            ushort_t hh = f2b(v);
            Bh[nl * 136 + k] = hh;
            Bl[nl * 136 + k] = f2b(v - bits2f(hh));
        }
        __syncthreads();
        f32x4 acc[4];
#pragma unroll
        for (int nt = 0; nt < 4; ++nt) acc[nt] = (f32x4){0.f, 0.f, 0.f, 0.f};
        for (int kk = 0; kk < 128; kk += 32) {
            short8 ah = *(const short8*)&Ah[(w * 16 + l16) * 136 + kk + quad * 8];
            short8 al = *(const short8*)&Al[(w * 16 + l16) * 136 + kk + quad * 8];
#pragma unroll
            for (int nt = 0; nt < 4; ++nt) {
                short8 bh = *(const short8*)&Bh[(nt * 16 + l16) * 136 + kk + quad * 8];
                short8 bl = *(const short8*)&Bl[(nt * 16 + l16) * 136 + kk + quad * 8];
                acc[nt] = __builtin_amdgcn_mfma_f32_16x16x32_bf16(ah, bh, acc[nt], 0, 0, 0);
                acc[nt] = __builtin_amdgcn_mfma_f32_16x16x32_bf16(ah, bl, acc[nt], 0, 0, 0);
                acc[nt] = __builtin_amdgcn_mfma_f32_16x16x32_bf16(al, bh, acc[nt], 0, 0, 0);
            }
        }
#pragma unroll
        for (int nt = 0; nt < 4; ++nt) {
            int col = nc * 64 + nt * 16 + l16;
            float bias = loadF(b1, b1off + col, isf32);
#pragma unroll
            for (int r = 0; r < 4; ++r) {
                int row = m0 + w * 16 + quad * 4 + r;
                if (row < NN) {
                    float v = fmaxf(acc[nt][r] + bias, 0.f);
                    ushort_t hh = f2b(v);
                    mid_hi[(long long)row * 256 + col] = hh;
                    mid_lo[(long long)row * 256 + col] = f2b(v - bits2f(hh));
                }
            }
        }
    }
}

// GEMM2: h2[NN x 128] = mid @ W2 + b2 (split-precision). One block per 64-row
// m-tile, full N=128; K=256 in 2 chunks; B in 2 N-chunks. h2 overwrites
// mid_hi's rows (hbuf overlay) only in the epilogue.
__global__ __launch_bounds__(256) void gemm2_k(
        const ushort_t* mid_hi, const ushort_t* mid_lo,
        const void* __restrict__ W2, const void* __restrict__ b2,
        const int* __restrict__ fl, int layer,
        float* h2) {
    __shared__ ushort_t Ah[64 * 136], Al[64 * 136];
    __shared__ ushort_t Bh[64 * 136], Bl[64 * 136];
    int isf32 = *fl;
    int m0 = blockIdx.x * 64;
    long long w2off = (long long)layer * 2 * D * D;
    long long b2off = (long long)layer * D;
    int w = threadIdx.x >> 6, lane = threadIdx.x & 63;
    int quad = lane >> 4, l16 = lane & 15;
    f32x4 acc[8];
#pragma unroll
    for (int t = 0; t < 8; ++t) acc[t] = (f32x4){0.f, 0.f, 0.f, 0.f};
    for (int kc = 0; kc < 2; ++kc) {
        __syncthreads();  // prior A/B reads done
        for (int i = threadIdx.x; i < 64 * 128; i += 256) {
            int r = i >> 7, kl = i & 127;
            int gr = m0 + r;
            long long gi = (long long)gr * 256 + kc * 128 + kl;
            Ah[r * 136 + kl] = (gr < NN) ? mid_hi[gi] : (ushort_t)0;
            Al[r * 136 + kl] = (gr < NN) ? mid_lo[gi] : (ushort_t)0;
        }
        for (int nc = 0; nc < 2; ++nc) {
            __syncthreads();  // A staged / prior B reads done
            for (int i = threadIdx.x; i < 64 * 128; i += 256) {
                int nl = i & 63, kl = i >> 6;
                float v = loadF(W2, w2off + (long long)(kc * 128 + kl) * D + nc * 64 + nl, isf32);
                ushort_t hh = f2b(v);
                Bh[nl * 136 + kl] = hh;
                Bl[nl * 136 + kl] = f2b(v - bits2f(hh));
            }
            __syncthreads();
            for (int kk = 0; kk < 128; kk += 32) {
                short8 ah = *(const short8*)&Ah[(w * 16 + l16) * 136 + kk + quad * 8];
                short8 al = *(const short8*)&Al[(w * 16 + l16) * 136 + kk + quad * 8];
#pragma unroll
                for (int nt = 0; nt < 4; ++nt) {
                    short8 bh = *(const short8*)&Bh[(nt * 16 + l16) * 136 + kk + quad * 8];
                    short8 bl = *(const short8*)&Bl[(nt * 16 + l16) * 136 + kk + quad * 8];
                    int t = nc * 4 + nt;
                    acc[t] = __builtin_amdgcn_mfma_f32_16x16x32_bf16(ah, bh, acc[t], 0, 0, 0);
                    acc[t] = __builtin_amdgcn_mfma_f32_16x16x32_bf16(ah, bl, acc[t], 0, 0, 0);
                    acc[t] = __builtin_amdgcn_mfma_f32_16x16x32_bf16(al, bh, acc[t], 0, 0, 0);
                }
            }
        }
    }
#pragma unroll
    for (int nc = 0; nc < 2; ++nc)
#pragma unroll
        for (int nt = 0; nt < 4; ++nt) {
            int col = nc * 64 + nt * 16 + l16;
            float bias = loadF(b2, b2off + col, isf32);
#pragma unroll
            for (int r = 0; r < 4; ++r) {
                int row = m0 + w * 16 + quad * 4 + r;
                if (row < NN)
                    h2[(long long)row * D + col] = acc[nc * 4 + nt][r] + bias;
            }
        }
}

__global__ void bnstats_k(const float* __restrict__ h2, float* __restrict__ stats) {
    __shared__ float ss[256];
    __shared__ float sq[256];
    int tid = threadIdx.x;
    float s = 0.f, q = 0.f;
    int stride = gridDim.x * 256;
    for (int idx = blockIdx.x * 256 + tid; idx < NN * D; idx += stride) {
        float v = h2[idx];
        s += v;
        q += v * v;
    }
    ss[tid] = s;
    sq[tid] = q;
    __syncthreads();
    if (tid < D) {
        atomicAdd(&stats[tid], ss[tid] + ss[tid + D]);
        atomicAdd(&stats[D + tid], sq[tid] + sq[tid + D]);
    }
}

// in-place BN (+ReLU); h2/hout may be the same buffer (same-index)
__global__ void bnnorm_k(const float* h2,
                         const float* __restrict__ stats,
                         const void* __restrict__ gamma,
                         const void* __restrict__ beta,
                         const int* __restrict__ fl,
                         int layer,
                         float* hout,
                         int relu) {
    int isf32 = *fl;
    long long goff = (long long)layer * D;
    int idx = blockIdx.x * 256 + threadIdx.x;
    if (idx >= NN * D) return;
    int f = idx & 127;
    float mu = stats[f] * (1.f / NN);
    float var = fmaxf(stats[D + f] * (1.f / NN) - mu * mu, 0.f);
    float rs = rsqrtf(var + 1e-5f);
    float v = (h2[idx] - mu) * rs * loadF(gamma, goff + f, isf32) +
              loadF(beta, goff + f, isf32);
    if (relu) v = fmaxf(v, 0.f);
    hout[idx] = v;
}

extern "C" void kernel_launch(void* const* d_in, const int* in_sizes, int n_in,
                              void* d_out, int out_size, void* d_ws, size_t ws_size,
                              hipStream_t stream) {
    const int* x     = (const int*)d_in[0];
    const int* ei    = (const int*)d_in[1];
    const int* ea    = (const int*)d_in[2];
    const void* atom = d_in[3];
    const void* chir = d_in[4];
    const void* hyb  = d_in[5];
    const void* e1   = d_in[6];
    const void* e2   = d_in[7];
    const void* W1   = d_in[8];
    const void* b1   = d_in[9];
    const void* W2   = d_in[10];
    const void* b2   = d_in[11];
    const void* gm   = d_in[12];
    const void* bt   = d_in[13];

    const size_t ND = (size_t)NN * D;

    // ws: [stats 1KB][flag][pad->2048][hbuf ND*4: h f32 / mid_hi bf16 / h2 f32]
    //     [csr NE*4][row_start][deg][tmp][next][partial]   ~28.9MB total
    char* base = (char*)d_ws;
    float* stats   = (float*)base;
    int*   flag    = (int*)(base + 1024);
    char*  p       = base + 2048;
    float* hbuf    = (float*)p;  p += ND * 4;
    int* csr       = (int*)p;    p += (size_t)NE * 4;
    int* row_start = (int*)p;    p += (size_t)(NN + 1) * 4 + 12;
    int* deg       = (int*)p;    p += (size_t)NN * 4;
    int* tmp       = (int*)p;    p += (size_t)NN * 4;
    int* next      = (int*)p;    p += (size_t)NN * 4;
    int* partial   = (int*)p;

    float* agg       = (float*)d_out;        // NN*128 f32
    ushort_t* mid_lo = (ushort_t*)d_out;     // NN*256 bf16, overlays agg (disjoint lifetime)
    ushort_t* mid_hi = (ushort_t*)hbuf;      // NN*256 bf16, overlays h (disjoint lifetime)

    const int ND_BLOCKS = (NN * D + 255) / 256;   // 25000
    const int E_BLOCKS  = (NE + 255) / 256;       // 2344
    const int N_BLOCKS  = (NN + 255) / 256;       // 196
    const int M_TILES   = (NN + 63) / 64;         // 782

    detect_k<<<1, 256, 0, stream>>>(atom, flag);

    zero_i<<<N_BLOCKS, 256, 0, stream>>>(deg, NN);
    hist_k<<<E_BLOCKS, 256, 0, stream>>>(ei, deg);
    scan1_k<<<N_BLOCKS, 256, 0, stream>>>(deg, tmp, partial);
    scan2_k<<<1, 256, 0, stream>>>(partial, N_BLOCKS);
    scan3_k<<<N_BLOCKS, 256, 0, stream>>>(tmp, partial, deg, row_start, next);
    fill_k<<<E_BLOCKS, 256, 0, stream>>>(ei, ea, next, csr);

    embed_k<<<ND_BLOCKS, 256, 0, stream>>>(x, atom, chir, hyb, flag, hbuf);

    for (int l = 0; l < NL; ++l) {
        zero_f<<<1, 256, 0, stream>>>(stats, 2 * D);
        aggr_k<<<NN / 4, 256, 0, stream>>>(hbuf, row_start, csr, e1, e2, flag, l, agg);
        gemm1_k<<<M_TILES, 256, 0, stream>>>(agg, W1, b1, flag, l, mid_hi, mid_lo);
        gemm2_k<<<M_TILES, 256, 0, stream>>>(mid_hi, mid_lo, W2, b2, flag, l, hbuf);
        bnstats_k<<<256, 256, 0, stream>>>(hbuf, stats);
        int last = (l == NL - 1);
        bnnorm_k<<<ND_BLOCKS, 256, 0, stream>>>(hbuf, stats, gm, bt, flag, l,
            last ? (float*)d_out : hbuf, last ? 0 : 1);
    }
}

// Round 8
// 2026.764 us; speedup vs baseline: 2.0717x; 1.0687x over previous
//
#include <hip/hip_runtime.h>
#include <hip/hip_bf16.h>

#define NN 50000
#define NE 600000
#define D 128
#define NL 5

typedef __hip_bfloat16 bf16;
typedef unsigned short ushort_t;
typedef __attribute__((ext_vector_type(8))) short short8;
typedef __attribute__((ext_vector_type(4))) float f32x4;

__device__ __forceinline__ float b2f(bf16 v) { return __bfloat162float(v); }

__device__ __forceinline__ float loadF(const void* p, long long i, int isf32) {
    if (isf32) return ((const float*)p)[i];
    return b2f(((const bf16*)p)[i]);
}

__device__ __forceinline__ ushort_t f2b(float x) {
    union { float f; unsigned u; } v; v.f = x;
    unsigned r = v.u + 0x7FFF + ((v.u >> 16) & 1);
    return (ushort_t)(r >> 16);
}
__device__ __forceinline__ float bits2f(ushort_t h) {
    union { unsigned u; float f; } v; v.u = ((unsigned)h) << 16;
    return v.f;
}

__global__ void detect_k(const void* __restrict__ atom, int* __restrict__ flag) {
    __shared__ int vote;
    if (threadIdx.x == 0) vote = 0;
    __syncthreads();
    unsigned short u = ((const unsigned short*)atom)[threadIdx.x];
    unsigned short ex = (u >> 7) & 0xFF;
    if (ex >= 0x90) atomicOr(&vote, 1);
    __syncthreads();
    if (threadIdx.x == 0) *flag = vote;
}

__global__ void zero_f(float* __restrict__ p, int n) {
    int i = blockIdx.x * 256 + threadIdx.x;
    if (i < n) p[i] = 0.f;
}
__global__ void zero_i(int* __restrict__ p, int n) {
    int i = blockIdx.x * 256 + threadIdx.x;
    if (i < n) p[i] = 0;
}
// norm = identity: scale=1, shift=0
__global__ void initnorm_k(float* __restrict__ norm) {
    int t = threadIdx.x;
    norm[t] = (t < D) ? 1.f : 0.f;
}

// ---------------- CSR build ----------------
__global__ void hist_k(const int* __restrict__ ei, int* __restrict__ deg) {
    int e = blockIdx.x * 256 + threadIdx.x;
    if (e < NE) atomicAdd(&deg[ei[NE + e]], 1);
}

__global__ void scan1_k(const int* __restrict__ deg, int* __restrict__ tmp,
                        int* __restrict__ partial) {
    __shared__ int s[256];
    int t = threadIdx.x;
    int i = blockIdx.x * 256 + t;
    int v = (i < NN) ? deg[i] : 0;
    s[t] = v;
    __syncthreads();
    for (int off = 1; off < 256; off <<= 1) {
        int x = (t >= off) ? s[t - off] : 0;
        __syncthreads();
        s[t] += x;
        __syncthreads();
    }
    if (i < NN) tmp[i] = s[t];
    if (t == 255) partial[blockIdx.x] = s[255];
}

__global__ void scan2_k(int* __restrict__ partial, int nb) {
    __shared__ int s[256];
    int t = threadIdx.x;
    int v = (t < nb) ? partial[t] : 0;
    s[t] = v;
    __syncthreads();
    for (int off = 1; off < 256; off <<= 1) {
        int x = (t >= off) ? s[t - off] : 0;
        __syncthreads();
        s[t] += x;
        __syncthreads();
    }
    int excl = s[t] - v;
    __syncthreads();
    if (t < nb) partial[t] = excl;
}

__global__ void scan3_k(const int* __restrict__ tmp, const int* __restrict__ partial,
                        const int* __restrict__ deg,
                        int* __restrict__ row_start, int* __restrict__ next) {
    int i = blockIdx.x * 256 + threadIdx.x;
    if (i >= NN) return;
    int incl = tmp[i] + partial[i >> 8];
    row_start[i + 1] = incl;
    next[i] = incl - deg[i];
    if (i == 0) row_start[0] = 0;
}

__global__ void fill_k(const int* __restrict__ ei, const int* __restrict__ ea,
                       int* __restrict__ next, int* __restrict__ csr) {
    int e = blockIdx.x * 256 + threadIdx.x;
    if (e >= NE) return;
    int src = ei[e];
    int dst = ei[NE + e];
    int c = ea[2 * e] * 4 + ea[2 * e + 1];
    int pos = atomicAdd(&next[dst], 1);
    csr[pos] = src | (c << 16);
}

// ---------------- forward ----------------
__global__ void embed_k(const int* __restrict__ x,
                        const void* __restrict__ atom,
                        const void* __restrict__ chir,
                        const void* __restrict__ hyb,
                        const int* __restrict__ fl,
                        float* __restrict__ h) {
    int isf32 = *fl;
    int idx = blockIdx.x * 256 + threadIdx.x;
    if (idx >= NN * D) return;
    int n = idx >> 7, f = idx & 127;
    h[idx] = loadF(atom, (long long)x[n * 3 + 0] * D + f, isf32) +
             loadF(chir, (long long)x[n * 3 + 1] * D + f, isf32) +
             loadF(hyb,  (long long)x[n * 3 + 2] * D + f, isf32);
}

// one wave per node; applies BN(scale,shift)+optional ReLU to gathered h rows
__global__ __launch_bounds__(256) void aggr_k(
        const float* __restrict__ h,
        const float* __restrict__ norm,   // [scale 128][shift 128]
        const int* __restrict__ row_start,
        const int* __restrict__ csr,
        const void* __restrict__ e1, const void* __restrict__ e2,
        const int* __restrict__ fl, int layer, int relu,
        float* __restrict__ agg) {
    __shared__ float comb[24 * D];
    int isf32 = *fl;
    long long e1off = (long long)layer * 6 * D;
    long long e2off = (long long)layer * 4 * D;
    for (int i = threadIdx.x; i < 24 * D; i += 256) {
        int c = i >> 7, f = i & 127;
        comb[i] = loadF(e1, e1off + (c >> 2) * D + f, isf32) +
                  loadF(e2, e2off + (c & 3) * D + f, isf32);
    }
    __syncthreads();
    int n = blockIdx.x * 4 + (threadIdx.x >> 6);
    int lane = threadIdx.x & 63;
    float s0 = norm[lane],      t0 = norm[D + lane];
    float s1 = norm[lane + 64], t1 = norm[D + lane + 64];
    int beg = row_start[n], end = row_start[n + 1];
    float v0 = 0.f, v1 = 0.f;
    int i = beg;
    for (; i + 1 < end; i += 2) {
        int pka = csr[i], pkb = csr[i + 1];
        const float* ha = h + (long long)(pka & 0xFFFF) * D;
        const float* hb = h + (long long)(pkb & 0xFFFF) * D;
        int ca = pka >> 16, cb = pkb >> 16;
        float a0 = fmaf(ha[lane],      s0, t0);
        float a1 = fmaf(ha[lane + 64], s1, t1);
        float b0 = fmaf(hb[lane],      s0, t0);
        float b1v = fmaf(hb[lane + 64], s1, t1);
        if (relu) {
            a0 = fmaxf(a0, 0.f); a1 = fmaxf(a1, 0.f);
            b0 = fmaxf(b0, 0.f); b1v = fmaxf(b1v, 0.f);
        }
        v0 += a0 + comb[ca * D + lane] + b0 + comb[cb * D + lane];
        v1 += a1 + comb[ca * D + lane + 64] + b1v + comb[cb * D + lane + 64];
    }
    if (i < end) {
        int pk = csr[i];
        const float* hr = h + (long long)(pk & 0xFFFF) * D;
        int c = pk >> 16;
        float a0 = fmaf(hr[lane],      s0, t0);
        float a1 = fmaf(hr[lane + 64], s1, t1);
        if (relu) { a0 = fmaxf(a0, 0.f); a1 = fmaxf(a1, 0.f); }
        v0 += a0 + comb[c * D + lane];
        v1 += a1 + comb[c * D + lane + 64];
    }
    agg[(long long)n * D + lane]      = v0;
    agg[(long long)n * D + lane + 64] = v1;
}

// Fused MLP: h2 = relu(agg@W1+b1)@W2 + b2, mid stays in LDS.
// One block per 64-row tile; split-precision bf16 MFMA (3 products).
// Also accumulates per-feature sum/sumsq into stats via block reduction.
__global__ __launch_bounds__(256) void mlp_k(
        const float* __restrict__ agg,
        const void* __restrict__ W1, const void* __restrict__ b1,
        const void* __restrict__ W2, const void* __restrict__ b2,
        const int* __restrict__ fl, int layer,
        float* __restrict__ h2, float* __restrict__ stats) {
    __shared__ ushort_t Ah[64 * 136], Al[64 * 136];
    __shared__ ushort_t Bh[9216], Bl[9216];   // union: B1 [64n][136] / B2 [128n][72]
    __shared__ ushort_t Mh[64 * 72], Ml[64 * 72];
    __shared__ float SS[2 * D];
    int isf32 = *fl;
    int m0 = blockIdx.x * 64;
    long long w1off = (long long)layer * D * 2 * D;
    long long b1off = (long long)layer * 2 * D;
    long long w2off = (long long)layer * 2 * D * D;
    long long b2off = (long long)layer * D;
    int tid = threadIdx.x;
    SS[tid] = 0.f;
    // stage A (agg rows, split hi/lo)
    for (int i = tid; i < 64 * 128; i += 256) {
        int r = i >> 7, c = i & 127;
        int gr = m0 + r;
        float v = (gr < NN) ? agg[(long long)gr * D + c] : 0.f;
        ushort_t hh = f2b(v);
        Ah[r * 136 + c] = hh;
        Al[r * 136 + c] = f2b(v - bits2f(hh));
    }
    int w = tid >> 6, lane = tid & 63;
    int quad = lane >> 4, l16 = lane & 15;
    f32x4 acc[8];
#pragma unroll
    for (int t = 0; t < 8; ++t) acc[t] = (f32x4){0.f, 0.f, 0.f, 0.f};

    for (int nc = 0; nc < 4; ++nc) {
        __syncthreads();  // A staged (nc=0) / prior B,M reads done
        // stage B1 chunk: W1[0:128, nc*64 .. +64] as [n][k]
        for (int i = tid; i < 64 * 128; i += 256) {
            int nl = i & 63, k = i >> 6;
            float v = loadF(W1, w1off + (long long)k * 256 + nc * 64 + nl, isf32);
            ushort_t hh = f2b(v);
            Bh[nl * 136 + k] = hh;
            Bl[nl * 136 + k] = f2b(v - bits2f(hh));
        }
        __syncthreads();
        // gemm1: mid chunk (64 rows x 64 cols)
        f32x4 macc[4];
#pragma unroll
        for (int nt = 0; nt < 4; ++nt) macc[nt] = (f32x4){0.f, 0.f, 0.f, 0.f};
        for (int kk = 0; kk < 128; kk += 32) {
            short8 ah = *(const short8*)&Ah[(w * 16 + l16) * 136 + kk + quad * 8];
            short8 al = *(const short8*)&Al[(w * 16 + l16) * 136 + kk + quad * 8];
#pragma unroll
            for (int nt = 0; nt < 4; ++nt) {
                short8 bh = *(const short8*)&Bh[(nt * 16 + l16) * 136 + kk + quad * 8];
                short8 bl = *(const short8*)&Bl[(nt * 16 + l16) * 136 + kk + quad * 8];
                macc[nt] = __builtin_amdgcn_mfma_f32_16x16x32_bf16(ah, bh, macc[nt], 0, 0, 0);
                macc[nt] = __builtin_amdgcn_mfma_f32_16x16x32_bf16(ah, bl, macc[nt], 0, 0, 0);
                macc[nt] = __builtin_amdgcn_mfma_f32_16x16x32_bf16(al, bh, macc[nt], 0, 0, 0);
            }
        }
        __syncthreads();  // B1 reads done before B2 overwrite; M reads of prev nc done
        // bias + relu + split -> mid LDS [m][k-in-chunk]
#pragma unroll
        for (int nt = 0; nt < 4; ++nt) {
            float bias = loadF(b1, b1off + nc * 64 + nt * 16 + l16, isf32);
#pragma unroll
            for (int r = 0; r < 4; ++r) {
                float v = fmaxf(macc[nt][r] + bias, 0.f);
                ushort_t hh = f2b(v);
                int m = w * 16 + quad * 4 + r;
                Mh[m * 72 + nt * 16 + l16] = hh;
                Ml[m * 72 + nt * 16 + l16] = f2b(v - bits2f(hh));
            }
        }
        // stage B2 chunk: W2[nc*64 .. +64, 0:128] as [n][k2]
        for (int i = tid; i < 64 * 128; i += 256) {
            int nl = i & 127, k2 = i >> 7;
            float v = loadF(W2, w2off + (long long)(nc * 64 + k2) * D + nl, isf32);
            ushort_t hh = f2b(v);
            Bh[nl * 72 + k2] = hh;
            Bl[nl * 72 + k2] = f2b(v - bits2f(hh));
        }
        __syncthreads();
        // gemm2 partial: h2 += mid_chunk @ B2_chunk
        for (int kk = 0; kk < 64; kk += 32) {
            short8 ah = *(const short8*)&Mh[(w * 16 + l16) * 72 + kk + quad * 8];
            short8 al = *(const short8*)&Ml[(w * 16 + l16) * 72 + kk + quad * 8];
#pragma unroll
            for (int nc2 = 0; nc2 < 2; ++nc2)
#pragma unroll
                for (int nt = 0; nt < 4; ++nt) {
                    short8 bh = *(const short8*)&Bh[(nc2 * 64 + nt * 16 + l16) * 72 + kk + quad * 8];
                    short8 bl = *(const short8*)&Bl[(nc2 * 64 + nt * 16 + l16) * 72 + kk + quad * 8];
                    int t = nc2 * 4 + nt;
                    acc[t] = __builtin_amdgcn_mfma_f32_16x16x32_bf16(ah, bh, acc[t], 0, 0, 0);
                    acc[t] = __builtin_amdgcn_mfma_f32_16x16x32_bf16(ah, bl, acc[t], 0, 0, 0);
                    acc[t] = __builtin_amdgcn_mfma_f32_16x16x32_bf16(al, bh, acc[t], 0, 0, 0);
                }
        }
    }
    // epilogue: bias, store h2, block-reduce stats
#pragma unroll
    for (int t = 0; t < 8; ++t) {
        int col = (t >> 2) * 64 + (t & 3) * 16 + l16;
        float bias = loadF(b2, b2off + col, isf32);
        float s = 0.f, q = 0.f;
#pragma unroll
        for (int r = 0; r < 4; ++r) {
            int row = m0 + w * 16 + quad * 4 + r;
            if (row < NN) {
                float v = acc[t][r] + bias;
                h2[(long long)row * D + col] = v;
                s += v; q += v * v;
            }
        }
        atomicAdd(&SS[col], s);
        atomicAdd(&SS[D + col], q);
    }
    __syncthreads();
    atomicAdd(&stats[tid], SS[tid]);
}

// stats -> (scale, shift) for this layer; re-zero stats for next layer
__global__ void finalize_k(float* __restrict__ stats,
                           const void* __restrict__ gamma,
                           const void* __restrict__ beta,
                           const int* __restrict__ fl, int layer,
                           float* __restrict__ norm) {
    int isf32 = *fl;
    int t = threadIdx.x;
    if (t < D) {
        float mu = stats[t] * (1.f / NN);
        float var = fmaxf(stats[D + t] * (1.f / NN) - mu * mu, 0.f);
        float rs = rsqrtf(var + 1e-5f);
        float sc = rs * loadF(gamma, (long long)layer * D + t, isf32);
        float sh = loadF(beta, (long long)layer * D + t, isf32) - mu * sc;
        norm[t] = sc;
        norm[D + t] = sh;
    }
    stats[t] = 0.f;
}

// final: out = scale*h2 + shift (no relu)
__global__ void apply_k(const float* __restrict__ h2,
                        const float* __restrict__ norm,
                        float* __restrict__ out) {
    int idx = blockIdx.x * 256 + threadIdx.x;
    if (idx >= NN * D) return;
    int f = idx & 127;
    out[idx] = fmaf(h2[idx], norm[f], norm[D + f]);
}

extern "C" void kernel_launch(void* const* d_in, const int* in_sizes, int n_in,
                              void* d_out, int out_size, void* d_ws, size_t ws_size,
                              hipStream_t stream) {
    const int* x     = (const int*)d_in[0];
    const int* ei    = (const int*)d_in[1];
    const int* ea    = (const int*)d_in[2];
    const void* atom = d_in[3];
    const void* chir = d_in[4];
    const void* hyb  = d_in[5];
    const void* e1   = d_in[6];
    const void* e2   = d_in[7];
    const void* W1   = d_in[8];
    const void* b1   = d_in[9];
    const void* W2   = d_in[10];
    const void* b2   = d_in[11];
    const void* gm   = d_in[12];
    const void* bt   = d_in[13];

    const size_t ND = (size_t)NN * D;

    // ws: [stats 256f][norm 256f][flag][pad->4096][hbuf ND f32][csr][row_start][deg][tmp][next][partial]
    char* base = (char*)d_ws;
    float* stats   = (float*)base;
    float* norm    = (float*)(base + 1024);
    int*   flag    = (int*)(base + 2048);
    char*  p       = base + 4096;
    float* hbuf    = (float*)p;  p += ND * 4;
    int* csr       = (int*)p;    p += (size_t)NE * 4;
    int* row_start = (int*)p;    p += (size_t)(NN + 1) * 4 + 12;
    int* deg       = (int*)p;    p += (size_t)NN * 4;
    int* tmp       = (int*)p;    p += (size_t)NN * 4;
    int* next      = (int*)p;    p += (size_t)NN * 4;
    int* partial   = (int*)p;

    float* aggbuf = (float*)d_out;   // scratch all layers; overwritten by apply_k at end

    const int ND_BLOCKS = (NN * D + 255) / 256;   // 25000
    const int E_BLOCKS  = (NE + 255) / 256;       // 2344
    const int N_BLOCKS  = (NN + 255) / 256;       // 196
    const int M_TILES   = (NN + 63) / 64;         // 782

    detect_k<<<1, 256, 0, stream>>>(atom, flag);

    zero_i<<<N_BLOCKS, 256, 0, stream>>>(deg, NN);
    hist_k<<<E_BLOCKS, 256, 0, stream>>>(ei, deg);
    scan1_k<<<N_BLOCKS, 256, 0, stream>>>(deg, tmp, partial);
    scan2_k<<<1, 256, 0, stream>>>(partial, N_BLOCKS);
    scan3_k<<<N_BLOCKS, 256, 0, stream>>>(tmp, partial, deg, row_start, next);
    fill_k<<<E_BLOCKS, 256, 0, stream>>>(ei, ea, next, csr);

    embed_k<<<ND_BLOCKS, 256, 0, stream>>>(x, atom, chir, hyb, flag, hbuf);
    initnorm_k<<<1, 256, 0, stream>>>(norm);
    zero_f<<<1, 256, 0, stream>>>(stats, 2 * D);

    for (int l = 0; l < NL; ++l) {
        aggr_k<<<NN / 4, 256, 0, stream>>>(hbuf, norm, row_start, csr,
                                           e1, e2, flag, l, (l > 0) ? 1 : 0, aggbuf);
        mlp_k<<<M_TILES, 256, 0, stream>>>(aggbuf, W1, b1, W2, b2, flag, l,
                                           hbuf, stats);
        finalize_k<<<1, 256, 0, stream>>>(stats, gm, bt, flag, l, norm);
    }
    apply_k<<<ND_BLOCKS, 256, 0, stream>>>(hbuf, norm, (float*)d_out);
}

// Round 9
// 821.911 us; speedup vs baseline: 5.1085x; 2.4659x over previous
//
#include <hip/hip_runtime.h>
#include <hip/hip_bf16.h>

#define NN 50000
#define NE 600000
#define D 128
#define NL 5

typedef __hip_bfloat16 bf16;
typedef unsigned short ushort_t;
typedef _Float16 half_t;
typedef __attribute__((ext_vector_type(8))) _Float16 half8;
typedef __attribute__((ext_vector_type(8))) short short8;
typedef __attribute__((ext_vector_type(4))) float f32x4;
typedef __attribute__((ext_vector_type(2))) float f32x2;

__device__ __forceinline__ float b2f(bf16 v) { return __bfloat162float(v); }

__device__ __forceinline__ float loadF(const void* p, long long i, int isf32) {
    if (isf32) return ((const float*)p)[i];
    return b2f(((const bf16*)p)[i]);
}

__global__ void detect_k(const void* __restrict__ atom, int* __restrict__ flag) {
    __shared__ int vote;
    if (threadIdx.x == 0) vote = 0;
    __syncthreads();
    unsigned short u = ((const unsigned short*)atom)[threadIdx.x];
    unsigned short ex = (u >> 7) & 0xFF;
    if (ex >= 0x90) atomicOr(&vote, 1);
    __syncthreads();
    if (threadIdx.x == 0) *flag = vote;
}

__global__ void zero_f(float* __restrict__ p, int n) {
    int i = blockIdx.x * 256 + threadIdx.x;
    if (i < n) p[i] = 0.f;
}
__global__ void zero_i(int* __restrict__ p, int n) {
    int i = blockIdx.x * 256 + threadIdx.x;
    if (i < n) p[i] = 0;
}

// convert + transpose weights to fp16 once per launch:
// w1t[l][n<256][k<128] = W1[l][k][n];  w2t[l][n<128][k<256] = W2[l][k][n]
__global__ void prepw_k(const void* __restrict__ W1, const void* __restrict__ W2,
                        const int* __restrict__ fl,
                        half_t* __restrict__ w1t, half_t* __restrict__ w2t) {
    int isf32 = *fl;
    int idx = blockIdx.x * 256 + threadIdx.x;
    const int per = NL * 2 * D * D;  // 163840
    if (idx < per) {
        int l = idx / (2 * D * D);
        int r = idx % (2 * D * D);
        int n = r >> 7, k = r & 127;          // n<256, k<128
        w1t[idx] = (half_t)loadF(W1, (long long)l * 2 * D * D + (long long)k * 256 + n, isf32);
    } else if (idx < 2 * per) {
        int j = idx - per;
        int l = j / (2 * D * D);
        int r = j % (2 * D * D);
        int n = r >> 8, k = r & 255;          // n<128, k<256
        w2t[j] = (half_t)loadF(W2, (long long)l * 2 * D * D + (long long)k * D + n, isf32);
    }
}

// ---------------- CSR build ----------------
__global__ void hist_k(const int* __restrict__ ei, int* __restrict__ deg) {
    int e = blockIdx.x * 256 + threadIdx.x;
    if (e < NE) atomicAdd(&deg[ei[NE + e]], 1);
}

__global__ void scan1_k(const int* __restrict__ deg, int* __restrict__ tmp,
                        int* __restrict__ partial) {
    __shared__ int s[256];
    int t = threadIdx.x;
    int i = blockIdx.x * 256 + t;
    int v = (i < NN) ? deg[i] : 0;
    s[t] = v;
    __syncthreads();
    for (int off = 1; off < 256; off <<= 1) {
        int x = (t >= off) ? s[t - off] : 0;
        __syncthreads();
        s[t] += x;
        __syncthreads();
    }
    if (i < NN) tmp[i] = s[t];
    if (t == 255) partial[blockIdx.x] = s[255];
}

__global__ void scan2_k(int* __restrict__ partial, int nb) {
    __shared__ int s[256];
    int t = threadIdx.x;
    int v = (t < nb) ? partial[t] : 0;
    s[t] = v;
    __syncthreads();
    for (int off = 1; off < 256; off <<= 1) {
        int x = (t >= off) ? s[t - off] : 0;
        __syncthreads();
        s[t] += x;
        __syncthreads();
    }
    int excl = s[t] - v;
    __syncthreads();
    if (t < nb) partial[t] = excl;
}

__global__ void scan3_k(const int* __restrict__ tmp, const int* __restrict__ partial,
                        const int* __restrict__ deg,
                        int* __restrict__ row_start, int* __restrict__ next) {
    int i = blockIdx.x * 256 + threadIdx.x;
    if (i >= NN) return;
    int incl = tmp[i] + partial[i >> 8];
    row_start[i + 1] = incl;
    next[i] = incl - deg[i];
    if (i == 0) row_start[0] = 0;
}

__global__ void fill_k(const int* __restrict__ ei, const int* __restrict__ ea,
                       int* __restrict__ next, int* __restrict__ csr) {
    int e = blockIdx.x * 256 + threadIdx.x;
    if (e >= NE) return;
    int src = ei[e];
    int dst = ei[NE + e];
    int c = ea[2 * e] * 4 + ea[2 * e + 1];
    int pos = atomicAdd(&next[dst], 1);
    csr[pos] = src | (c << 16);
}

// ---------------- forward ----------------
// initial embedding -> fp16 hpost; thread handles 2 features
__global__ void embed_k(const int* __restrict__ x,
                        const void* __restrict__ atom,
                        const void* __restrict__ chir,
                        const void* __restrict__ hyb,
                        const int* __restrict__ fl,
                        half_t* __restrict__ hpost) {
    int isf32 = *fl;
    int idx = blockIdx.x * 256 + threadIdx.x;   // over NN*64
    if (idx >= NN * 64) return;
    int n = idx >> 6, fp = (idx & 63) * 2;
    long long i0 = (long long)x[n * 3 + 0] * D + fp;
    long long i1 = (long long)x[n * 3 + 1] * D + fp;
    long long i2 = (long long)x[n * 3 + 2] * D + fp;
    float v0 = loadF(atom, i0, isf32) + loadF(chir, i1, isf32) + loadF(hyb, i2, isf32);
    float v1 = loadF(atom, i0 + 1, isf32) + loadF(chir, i1 + 1, isf32) + loadF(hyb, i2 + 1, isf32);
    half_t* dst = hpost + (long long)n * D + fp;
    dst[0] = (half_t)v0;
    dst[1] = (half_t)v1;
}

// one wave per node, pure gather: agg[n,:] = sum_e (hpost[src,:] + comb[c,:])
// lane handles features (2*lane, 2*lane+1)
__global__ __launch_bounds__(256) void aggr_k(
        const half_t* __restrict__ h,
        const int* __restrict__ row_start,
        const int* __restrict__ csr,
        const void* __restrict__ e1, const void* __restrict__ e2,
        const int* __restrict__ fl, int layer,
        float* __restrict__ agg) {
    __shared__ float comb[24 * D];
    int isf32 = *fl;
    long long e1off = (long long)layer * 6 * D;
    long long e2off = (long long)layer * 4 * D;
    for (int i = threadIdx.x; i < 24 * D; i += 256) {
        int c = i >> 7, f = i & 127;
        comb[i] = loadF(e1, e1off + (c >> 2) * D + f, isf32) +
                  loadF(e2, e2off + (c & 3) * D + f, isf32);
    }
    __syncthreads();
    int n = blockIdx.x * 4 + (threadIdx.x >> 6);
    int lane = threadIdx.x & 63;
    const f32x2* comb2 = (const f32x2*)comb;
    int beg = row_start[n], end = row_start[n + 1];
    float v0 = 0.f, v1 = 0.f;
    int i = beg;
    for (; i + 1 < end; i += 2) {
        int pka = csr[i], pkb = csr[i + 1];
        unsigned ha = *(const unsigned*)(h + (long long)(pka & 0xFFFF) * D + 2 * lane);
        unsigned hb = *(const unsigned*)(h + (long long)(pkb & 0xFFFF) * D + 2 * lane);
        f32x2 ca = comb2[(pka >> 16) * 64 + lane];
        f32x2 cb = comb2[(pkb >> 16) * 64 + lane];
        half_t a0 = ((const half_t*)&ha)[0], a1 = ((const half_t*)&ha)[1];
        half_t b0 = ((const half_t*)&hb)[0], b1 = ((const half_t*)&hb)[1];
        v0 += (float)a0 + ca.x + (float)b0 + cb.x;
        v1 += (float)a1 + ca.y + (float)b1 + cb.y;
    }
    if (i < end) {
        int pk = csr[i];
        unsigned hv = *(const unsigned*)(h + (long long)(pk & 0xFFFF) * D + 2 * lane);
        f32x2 cc = comb2[(pk >> 16) * 64 + lane];
        v0 += (float)((const half_t*)&hv)[0] + cc.x;
        v1 += (float)((const half_t*)&hv)[1] + cc.y;
    }
    f32x2 out; out.x = v0; out.y = v1;
    *(f32x2*)(agg + (long long)n * D + 2 * lane) = out;
}

// Fused MLP, fp16 MFMA: h2 = relu(agg@W1+b1)@W2 + b2 (pre-BN, fp16 out)
// + per-feature stats. One block per 64-row tile. A direct from global.
__global__ __launch_bounds__(256) void mlp_k(
        const float* __restrict__ agg,
        const half_t* __restrict__ w1t, const half_t* __restrict__ w2t,
        const void* __restrict__ b1, const void* __restrict__ b2,
        const int* __restrict__ fl, int layer,
        half_t* __restrict__ h2, float* __restrict__ stats) {
    __shared__ ushort_t Bs[9216];      // B1 chunk [64][136] / B2 chunk [128][72]
    __shared__ ushort_t Ms[64 * 72];   // mid chunk [m][k], fp16 bits
    __shared__ float SS[2 * D];
    int isf32 = *fl;
    int m0 = blockIdx.x * 64;
    long long b1off = (long long)layer * 2 * D;
    long long b2off = (long long)layer * D;
    int tid = threadIdx.x;
    int w = tid >> 6, lane = tid & 63;
    int quad = lane >> 4, l16 = lane & 15;
    SS[tid] = 0.f;

    // A fragments direct from global (reused across all 4 N-chunks)
    int arow = m0 + w * 16 + l16;
    if (arow >= NN) arow = NN - 1;
    const float* ap = agg + (long long)arow * D + quad * 8;
    half8 afrag[4];
#pragma unroll
    for (int kk4 = 0; kk4 < 4; ++kk4) {
        f32x4 u0 = *(const f32x4*)(ap + kk4 * 32);
        f32x4 u1 = *(const f32x4*)(ap + kk4 * 32 + 4);
#pragma unroll
        for (int j = 0; j < 4; ++j) {
            afrag[kk4][j] = (half_t)u0[j];
            afrag[kk4][4 + j] = (half_t)u1[j];
        }
    }

    const half_t* w1p = w1t + (long long)layer * 256 * 128;
    const half_t* w2p = w2t + (long long)layer * 128 * 256;
    f32x4 acc[8];
#pragma unroll
    for (int t = 0; t < 8; ++t) acc[t] = (f32x4){0.f, 0.f, 0.f, 0.f};

    for (int nc = 0; nc < 4; ++nc) {
        __syncthreads();  // prev-iter Bs(B2)/Ms reads done; SS zeroed (nc=0)
        {   // stage B1 chunk: rows n = nc*64..+64 of w1t (each row 128 halfs)
            int r = tid >> 2, kq = (tid & 3) * 32;
            const ushort_t* src = (const ushort_t*)(w1p + (long long)(nc * 64 + r) * 128 + kq);
            ushort_t* dst = &Bs[r * 136 + kq];
#pragma unroll
            for (int t = 0; t < 4; ++t)
                *(short8*)(dst + t * 8) = *(const short8*)(src + t * 8);
        }
        __syncthreads();
        // gemm1 chunk: 64 rows x 64 cols
        f32x4 macc[4];
#pragma unroll
        for (int nt = 0; nt < 4; ++nt) macc[nt] = (f32x4){0.f, 0.f, 0.f, 0.f};
#pragma unroll
        for (int kk4 = 0; kk4 < 4; ++kk4) {
            half8 a = afrag[kk4];
#pragma unroll
            for (int nt = 0; nt < 4; ++nt) {
                half8 b = *(const half8*)&Bs[(nt * 16 + l16) * 136 + kk4 * 32 + quad * 8];
                macc[nt] = __builtin_amdgcn_mfma_f32_16x16x32_f16(a, b, macc[nt], 0, 0, 0);
            }
        }
        // bias + relu -> Ms (fp16 bits), C-layout -> A-layout via LDS
#pragma unroll
        for (int nt = 0; nt < 4; ++nt) {
            float bias = loadF(b1, b1off + nc * 64 + nt * 16 + l16, isf32);
#pragma unroll
            for (int r = 0; r < 4; ++r) {
                float v = fmaxf(macc[nt][r] + bias, 0.f);
                half_t hv = (half_t)v;
                Ms[(w * 16 + quad * 4 + r) * 72 + nt * 16 + l16] = *(ushort_t*)&hv;
            }
        }
        __syncthreads();  // gemm1 Bs reads + Ms writes done
        {   // stage B2 chunk: all 128 n-rows, k-cols nc*64..+64 of w2t
            int r = tid >> 1, kq = (tid & 1) * 32;
            const ushort_t* src = (const ushort_t*)(w2p + (long long)r * 256 + nc * 64 + kq);
            ushort_t* dst = &Bs[r * 72 + kq];
#pragma unroll
            for (int t = 0; t < 4; ++t)
                *(short8*)(dst + t * 8) = *(const short8*)(src + t * 8);
        }
        __syncthreads();
        // gemm2 partial: acc += mid_chunk @ W2_chunk
#pragma unroll
        for (int kk4 = 0; kk4 < 2; ++kk4) {
            half8 a = *(const half8*)&Ms[(w * 16 + l16) * 72 + kk4 * 32 + quad * 8];
#pragma unroll
            for (int t = 0; t < 8; ++t) {
                half8 b = *(const half8*)&Bs[((t >> 2) * 64 + (t & 3) * 16 + l16) * 72 + kk4 * 32 + quad * 8];
                acc[t] = __builtin_amdgcn_mfma_f32_16x16x32_f16(a, b, acc[t], 0, 0, 0);
            }
        }
    }
    // epilogue: bias, fp16 store, stats block-reduce
#pragma unroll
    for (int t = 0; t < 8; ++t) {
        int col = (t >> 2) * 64 + (t & 3) * 16 + l16;
        float bias = loadF(b2, b2off + col, isf32);
        float s = 0.f, q = 0.f;
#pragma unroll
        for (int r = 0; r < 4; ++r) {
            int row = m0 + w * 16 + quad * 4 + r;
            if (row < NN) {
                float v = acc[t][r] + bias;
                h2[(long long)row * D + col] = (half_t)v;
                s += v; q += v * v;
            }
        }
        atomicAdd(&SS[col], s);
        atomicAdd(&SS[D + col], q);
    }
    __syncthreads();
    atomicAdd(&stats[tid], SS[tid]);
}

// stats -> (scale, shift); re-zero stats
__global__ void finalize_k(float* __restrict__ stats,
                           const void* __restrict__ gamma,
                           const void* __restrict__ beta,
                           const int* __restrict__ fl, int layer,
                           float* __restrict__ norm) {
    int isf32 = *fl;
    int t = threadIdx.x;
    if (t < D) {
        float mu = stats[t] * (1.f / NN);
        float var = fmaxf(stats[D + t] * (1.f / NN) - mu * mu, 0.f);
        float rs = rsqrtf(var + 1e-5f);
        float sc = rs * loadF(gamma, (long long)layer * D + t, isf32);
        float sh = loadF(beta, (long long)layer * D + t, isf32) - mu * sc;
        norm[t] = sc;
        norm[D + t] = sh;
    }
    stats[t] = 0.f;
}

// BN apply (+ReLU) once per node-feature: hpost = relu(norm(h2)) fp16,
// or final f32 out (no relu). Thread handles 2 features.
__global__ void bnapply_k(const half_t* __restrict__ h2,
                          const float* __restrict__ norm,
                          half_t* __restrict__ hpost,
                          float* __restrict__ out,
                          int relu) {
    int idx = blockIdx.x * 256 + threadIdx.x;  // over NN*64
    if (idx >= NN * 64) return;
    int fp = (idx & 63) * 2;
    unsigned hv = *(const unsigned*)(h2 + (long long)(idx >> 6) * D + fp);
    float v0 = fmaf((float)((const half_t*)&hv)[0], norm[fp], norm[D + fp]);
    float v1 = fmaf((float)((const half_t*)&hv)[1], norm[fp + 1], norm[D + fp + 1]);
    if (relu) { v0 = fmaxf(v0, 0.f); v1 = fmaxf(v1, 0.f); }
    if (out) {
        f32x2 o; o.x = v0; o.y = v1;
        *(f32x2*)(out + (long long)(idx >> 6) * D + fp) = o;
    } else {
        half_t* dst = hpost + (long long)(idx >> 6) * D + fp;
        dst[0] = (half_t)v0;
        dst[1] = (half_t)v1;
    }
}

extern "C" void kernel_launch(void* const* d_in, const int* in_sizes, int n_in,
                              void* d_out, int out_size, void* d_ws, size_t ws_size,
                              hipStream_t stream) {
    const int* x     = (const int*)d_in[0];
    const int* ei    = (const int*)d_in[1];
    const int* ea    = (const int*)d_in[2];
    const void* atom = d_in[3];
    const void* chir = d_in[4];
    const void* hyb  = d_in[5];
    const void* e1   = d_in[6];
    const void* e2   = d_in[7];
    const void* W1   = d_in[8];
    const void* b1   = d_in[9];
    const void* W2   = d_in[10];
    const void* b2   = d_in[11];
    const void* gm   = d_in[12];
    const void* bt   = d_in[13];

    const size_t ND = (size_t)NN * D;

    // ws: [stats 1KB][norm 1KB][flag][pad->4096][hpost fp16][h2 fp16]
    //     [w1t fp16][w2t fp16][csr][row_start][deg][tmp][next][partial] ~30MB
    char* base = (char*)d_ws;
    float* stats   = (float*)base;
    float* norm    = (float*)(base + 1024);
    int*   flag    = (int*)(base + 2048);
    char*  p       = base + 4096;
    half_t* hpost  = (half_t*)p;  p += ND * 2;
    half_t* h2     = (half_t*)p;  p += ND * 2;
    half_t* w1t    = (half_t*)p;  p += (size_t)NL * 2 * D * D * 2;
    half_t* w2t    = (half_t*)p;  p += (size_t)NL * 2 * D * D * 2;
    int* csr       = (int*)p;     p += (size_t)NE * 4;
    int* row_start = (int*)p;     p += (size_t)(NN + 1) * 4 + 12;
    int* deg       = (int*)p;     p += (size_t)NN * 4;
    int* tmp       = (int*)p;     p += (size_t)NN * 4;
    int* next      = (int*)p;     p += (size_t)NN * 4;
    int* partial   = (int*)p;

    float* aggbuf = (float*)d_out;  // f32 scratch; final bnapply overwrites at end

    const int N2_BLOCKS = (NN * 64 + 255) / 256;  // 12500
    const int E_BLOCKS  = (NE + 255) / 256;       // 2344
    const int N_BLOCKS  = (NN + 255) / 256;       // 196
    const int M_TILES   = (NN + 63) / 64;         // 782
    const int PW_BLOCKS = (2 * NL * 2 * D * D + 255) / 256;  // 1280

    detect_k<<<1, 256, 0, stream>>>(atom, flag);
    prepw_k<<<PW_BLOCKS, 256, 0, stream>>>(W1, W2, flag, w1t, w2t);

    zero_i<<<N_BLOCKS, 256, 0, stream>>>(deg, NN);
    hist_k<<<E_BLOCKS, 256, 0, stream>>>(ei, deg);
    scan1_k<<<N_BLOCKS, 256, 0, stream>>>(deg, tmp, partial);
    scan2_k<<<1, 256, 0, stream>>>(partial, N_BLOCKS);
    scan3_k<<<N_BLOCKS, 256, 0, stream>>>(tmp, partial, deg, row_start, next);
    fill_k<<<E_BLOCKS, 256, 0, stream>>>(ei, ea, next, csr);

    embed_k<<<N2_BLOCKS, 256, 0, stream>>>(x, atom, chir, hyb, flag, hpost);
    zero_f<<<1, 256, 0, stream>>>(stats, 2 * D);

    for (int l = 0; l < NL; ++l) {
        aggr_k<<<NN / 4, 256, 0, stream>>>(hpost, row_start, csr, e1, e2, flag, l, aggbuf);
        mlp_k<<<M_TILES, 256, 0, stream>>>(aggbuf, w1t, w2t, b1, b2, flag, l, h2, stats);
        finalize_k<<<1, 256, 0, stream>>>(stats, gm, bt, flag, l, norm);
        int last = (l == NL - 1);
        bnapply_k<<<N2_BLOCKS, 256, 0, stream>>>(h2, norm,
            hpost, last ? (float*)d_out : (float*)nullptr, last ? 0 : 1);
    }
}